// Round 1
// 583.734 us; speedup vs baseline: 1.2525x; 1.2525x over previous
//
#include <hip/hip_runtime.h>

#define NODES 50000
#define EDGES 800000
#define H 96

typedef float floatx4 __attribute__((ext_vector_type(4)));
typedef unsigned short ushort8 __attribute__((ext_vector_type(8)));
typedef __bf16 bf16x8 __attribute__((ext_vector_type(8)));

static __device__ __forceinline__ unsigned short f2b(float f) {
    unsigned int u = __float_as_uint(f);
    u = u + 0x7fffu + ((u >> 16) & 1u);   // RNE
    return (unsigned short)(u >> 16);
}
static __device__ __forceinline__ float b2f(unsigned short u) {
    return __uint_as_float(((unsigned int)u) << 16);
}
static __device__ __forceinline__ float gelu_erf(float x) {
    return 0.5f * x * (1.0f + erff(x * 0.70710678118654752f));
}
static __device__ __forceinline__ bf16x8 pack_bf8(floatx4 a, floatx4 b) {
    union { ushort8 u; bf16x8 v; } r;
    #pragma unroll
    for (int j = 0; j < 4; ++j) { r.u[j] = f2b(a[j]); r.u[4 + j] = f2b(b[j]); }
    return r.v;
}

// ---------------- CSR build: histogram -> parallel scan -> cursor scatter ---
__global__ __launch_bounds__(256) void hist_deg(
    const int* __restrict__ dst, int* __restrict__ deg)
{
    const int e = blockIdx.x * 256 + threadIdx.x;
    if (e < EDGES) atomicAdd(&deg[dst[e]], 1);
}

// phase 1: per-block sums of deg (coalesced)
__global__ __launch_bounds__(256) void deg_block_sum(
    const int* __restrict__ deg, int* __restrict__ bsum)
{
    const int idx = blockIdx.x * 256 + threadIdx.x;
    int v = (idx < NODES) ? deg[idx] : 0;
    #pragma unroll
    for (int d = 32; d > 0; d >>= 1) v += __shfl_down(v, d);
    __shared__ int sh[4];
    if ((threadIdx.x & 63) == 0) sh[threadIdx.x >> 6] = v;
    __syncthreads();
    if (threadIdx.x == 0) bsum[blockIdx.x] = sh[0] + sh[1] + sh[2] + sh[3];
}

// phase 2: exclusive scan of the 196 block sums (one tiny block)
__global__ __launch_bounds__(256) void scan_bsum(
    const int* __restrict__ bsum, int* __restrict__ boff, int nb)
{
    __shared__ int sh[256];
    const int t = threadIdx.x;
    int v = (t < nb) ? bsum[t] : 0;
    sh[t] = v;
    __syncthreads();
    for (int d = 1; d < 256; d <<= 1) {
        int x = (t >= d) ? sh[t - d] : 0;
        __syncthreads();
        sh[t] += x;
        __syncthreads();
    }
    boff[t] = sh[t] - v;   // exclusive
}

// phase 3: per-block exclusive scan + block offset -> off, cursor
__global__ __launch_bounds__(256) void scan_expand(
    const int* __restrict__ deg, const int* __restrict__ boff,
    int* __restrict__ off, int* __restrict__ cursor)
{
    const int t = threadIdx.x;
    const int idx = blockIdx.x * 256 + t;
    int v = (idx < NODES) ? deg[idx] : 0;
    __shared__ int sh[256];
    sh[t] = v;
    __syncthreads();
    for (int d = 1; d < 256; d <<= 1) {
        int x = (t >= d) ? sh[t - d] : 0;
        __syncthreads();
        sh[t] += x;
        __syncthreads();
    }
    const int excl = sh[t] - v + boff[blockIdx.x];
    if (idx < NODES) { off[idx] = excl; cursor[idx] = excl; }
    if (idx == NODES - 1) off[NODES] = excl + v;
}

// scatter (e, src[e]) pairs -> one less dependent load in gather
__global__ __launch_bounds__(256) void build_csr2(
    const int* __restrict__ dst, const int* __restrict__ src,
    int* __restrict__ cursor, int2* __restrict__ csr)
{
    const int e = blockIdx.x * 256 + threadIdx.x;
    if (e < EDGES) {
        const int p = atomicAdd(&cursor[dst[e]], 1);
        int2 es; es.x = e; es.y = src[e];
        csr[p] = es;
    }
}

// ---------------- GEMM 1: h = gelu(x_feat @ W_pre + b) -> bf16 --------------
// fp32 A read + in-register bf16 convert (kills the cvt pass).
// mfma_f32_16x16x32_bf16: A[m=lane&15][k=quad*8+j]; B[k][n=lane&15];
// C/D col=lane&15, row=quad*4+r (m89/m91-verified).
__global__ __launch_bounds__(256) void gemm96_pre(
    const float* __restrict__ A,
    const float* __restrict__ W,
    const float* __restrict__ bias,
    unsigned short* __restrict__ outp,
    int nStrips)
{
    __shared__ unsigned short Wt[96][104];  // [n][k] bf16
    const int tid = threadIdx.x;
    #pragma unroll
    for (int j = 0; j < 36; ++j) {          // 9216 = 256*36
        const int f = tid + 256 * j;
        const int k = f / 96, n = f - k * 96;
        Wt[n][k] = f2b(W[f]);
    }
    __syncthreads();

    const int lane = tid & 63;
    const int quad = lane >> 4;
    const int l16  = lane & 15;

    bf16x8 Bf[3][6];
    float  bv[6];
    #pragma unroll
    for (int ks = 0; ks < 3; ++ks)
        #pragma unroll
        for (int nt = 0; nt < 6; ++nt)
            Bf[ks][nt] = *(const bf16x8*)(&Wt[nt * 16 + l16][ks * 32 + quad * 8]);
    #pragma unroll
    for (int nt = 0; nt < 6; ++nt) bv[nt] = bias[nt * 16 + l16];

    const int gwave  = (blockIdx.x * 256 + tid) >> 6;
    const int nWaves = (gridDim.x * 256) >> 6;

    for (int strip = gwave; strip < nStrips; strip += nWaves) {
        const int row0 = strip * 16;
        const float* Ap = A + (size_t)(row0 + l16) * H + quad * 8;

        bf16x8 Af[3];
        #pragma unroll
        for (int ks = 0; ks < 3; ++ks) {
            const floatx4 a0 = *(const floatx4*)(Ap + ks * 32);
            const floatx4 a1 = *(const floatx4*)(Ap + ks * 32 + 4);
            Af[ks] = pack_bf8(a0, a1);
        }

        floatx4 acc[6];
        #pragma unroll
        for (int nt = 0; nt < 6; ++nt) acc[nt] = (floatx4){0.f, 0.f, 0.f, 0.f};
        #pragma unroll
        for (int ks = 0; ks < 3; ++ks)
            #pragma unroll
            for (int nt = 0; nt < 6; ++nt)
                acc[nt] = __builtin_amdgcn_mfma_f32_16x16x32_bf16(Af[ks], Bf[ks][nt], acc[nt], 0, 0, 0);

        #pragma unroll
        for (int nt = 0; nt < 6; ++nt) {
            const int col = nt * 16 + l16;
            #pragma unroll
            for (int r = 0; r < 4; ++r) {
                const int row = row0 + quad * 4 + r;
                outp[(size_t)row * H + col] = f2b(gelu_erf(acc[nt][r] + bv[nt]));
            }
        }
    }
}

// ---------------- Pull-aggregate + residual: xb = x_feat + sum --------------
// 12 threads/node, 8 feats each; csr holds (e, src) pairs.
__global__ __launch_bounds__(256) void gather_nodes(
    const unsigned short* __restrict__ h,
    const float* __restrict__ bases,
    const int* __restrict__ off,
    const int2* __restrict__ csr,
    const float* __restrict__ x_feat,
    float* __restrict__ xb)
{
    const int t = blockIdx.x * 256 + threadIdx.x;
    const int n = t / 12;
    const int seg = t - n * 12;
    if (n >= NODES) return;
    const int i0 = off[n], i1 = off[n + 1];
    const int so8 = seg * 8;

    floatx4 acc0 = (floatx4){0.f, 0.f, 0.f, 0.f};
    floatx4 acc1 = (floatx4){0.f, 0.f, 0.f, 0.f};
    for (int i = i0; i < i1; ++i) {
        const int2 es = csr[i];
        const size_t eo = (size_t)es.x * H + so8;
        const floatx4 b0 = *(const floatx4*)(bases + eo);
        const floatx4 b1 = *(const floatx4*)(bases + eo + 4);
        const ushort8 hv = *(const ushort8*)(h + (size_t)es.y * H + so8);
        #pragma unroll
        for (int j = 0; j < 4; ++j) acc0[j] = fmaf(b0[j], b2f(hv[j]),     acc0[j]);
        #pragma unroll
        for (int j = 0; j < 4; ++j) acc1[j] = fmaf(b1[j], b2f(hv[4 + j]), acc1[j]);
    }

    const size_t no = (size_t)n * H + so8;
    const floatx4 x0 = *(const floatx4*)(x_feat + no);
    const floatx4 x1 = *(const floatx4*)(x_feat + no + 4);
    #pragma unroll
    for (int j = 0; j < 4; ++j) { acc0[j] += x0[j]; acc1[j] += x1[j]; }
    *(floatx4*)(xb + no)     = acc0;
    *(floatx4*)(xb + no + 4) = acc1;
}

// ---------------- Fused FFN: out = xb + gelu(gelu(xb@W1+b1)@W2+b2) ----------
// Wave computes its full 16x96 t-strip, redistributes via a wave-private LDS
// tile (no barrier: same-wave DS ordering), then runs the W2 stage + residual.
__global__ __launch_bounds__(256) void gemm96_dual(
    const float* __restrict__ A,        // xb fp32 [N][96]
    const float* __restrict__ W1, const float* __restrict__ b1,
    const float* __restrict__ W2, const float* __restrict__ b2,
    float* __restrict__ outp,
    int nStrips)
{
    __shared__ unsigned short Wt1[96][104];  // [n][k] bf16
    __shared__ unsigned short Wt2[96][104];
    __shared__ unsigned short Tt[4][16][120]; // per-wave t tile, 240B rows (16B-aligned, 8-bank spread)
    const int tid = threadIdx.x;
    #pragma unroll
    for (int j = 0; j < 36; ++j) {
        const int f = tid + 256 * j;
        const int k = f / 96, n = f - k * 96;
        Wt1[n][k] = f2b(W1[f]);
        Wt2[n][k] = f2b(W2[f]);
    }
    __syncthreads();

    const int lane = tid & 63;
    const int quad = lane >> 4;
    const int l16  = lane & 15;
    const int w    = tid >> 6;

    bf16x8 Bf1[3][6];
    float  bv1[6], bv2[6];
    #pragma unroll
    for (int ks = 0; ks < 3; ++ks)
        #pragma unroll
        for (int nt = 0; nt < 6; ++nt)
            Bf1[ks][nt] = *(const bf16x8*)(&Wt1[nt * 16 + l16][ks * 32 + quad * 8]);
    #pragma unroll
    for (int nt = 0; nt < 6; ++nt) {
        bv1[nt] = b1[nt * 16 + l16];
        bv2[nt] = b2[nt * 16 + l16];
    }

    const int gwave  = (blockIdx.x * 256 + tid) >> 6;
    const int nWaves = (gridDim.x * 256) >> 6;

    for (int strip = gwave; strip < nStrips; strip += nWaves) {
        const int row0 = strip * 16;
        const float* Ap = A + (size_t)(row0 + l16) * H + quad * 8;

        // stage 1: t = gelu(xb @ W1 + b1)
        bf16x8 Af[3];
        #pragma unroll
        for (int ks = 0; ks < 3; ++ks) {
            const floatx4 a0 = *(const floatx4*)(Ap + ks * 32);
            const floatx4 a1 = *(const floatx4*)(Ap + ks * 32 + 4);
            Af[ks] = pack_bf8(a0, a1);
        }
        floatx4 acc[6];
        #pragma unroll
        for (int nt = 0; nt < 6; ++nt) acc[nt] = (floatx4){0.f, 0.f, 0.f, 0.f};
        #pragma unroll
        for (int ks = 0; ks < 3; ++ks)
            #pragma unroll
            for (int nt = 0; nt < 6; ++nt)
                acc[nt] = __builtin_amdgcn_mfma_f32_16x16x32_bf16(Af[ks], Bf1[ks][nt], acc[nt], 0, 0, 0);

        // write t tile to wave-private LDS (C-layout -> A-layout redistribution)
        #pragma unroll
        for (int nt = 0; nt < 6; ++nt)
            #pragma unroll
            for (int r = 0; r < 4; ++r)
                Tt[w][quad * 4 + r][nt * 16 + l16] = f2b(gelu_erf(acc[nt][r] + bv1[nt]));

        // stage 2: out = xb + gelu(t @ W2 + b2)
        bf16x8 Tf[3];
        #pragma unroll
        for (int ks = 0; ks < 3; ++ks)
            Tf[ks] = *(const bf16x8*)(&Tt[w][l16][ks * 32 + quad * 8]);

        #pragma unroll
        for (int nt = 0; nt < 6; ++nt) acc[nt] = (floatx4){0.f, 0.f, 0.f, 0.f};
        #pragma unroll
        for (int ks = 0; ks < 3; ++ks)
            #pragma unroll
            for (int nt = 0; nt < 6; ++nt) {
                const bf16x8 Bf2 = *(const bf16x8*)(&Wt2[nt * 16 + l16][ks * 32 + quad * 8]);
                acc[nt] = __builtin_amdgcn_mfma_f32_16x16x32_bf16(Tf[ks], Bf2, acc[nt], 0, 0, 0);
            }

        #pragma unroll
        for (int nt = 0; nt < 6; ++nt) {
            const int col = nt * 16 + l16;
            #pragma unroll
            for (int r = 0; r < 4; ++r) {
                const int row = row0 + quad * 4 + r;
                const size_t o = (size_t)row * H + col;
                outp[o] = A[o] + gelu_erf(acc[nt][r] + bv2[nt]);
            }
        }
    }
}

extern "C" void kernel_launch(void* const* d_in, const int* in_sizes, int n_in,
                              void* d_out, int out_size, void* d_ws, size_t ws_size,
                              hipStream_t stream)
{
    const float* x_feat = (const float*)d_in[0];
    const float* bases  = (const float*)d_in[1];
    const float* W_pre  = (const float*)d_in[2];
    const float* b_pre  = (const float*)d_in[3];
    const float* W1     = (const float*)d_in[4];
    const float* b1     = (const float*)d_in[5];
    const float* W2     = (const float*)d_in[6];
    const float* b2     = (const float*)d_in[7];
    const int* src = (const int*)d_in[8];
    const int* dst = (const int*)d_in[9];

    char* ws = (char*)d_ws;
    int*            deg    = (int*)(ws);               // 200,000 B
    int*            off    = (int*)(ws + 200704);      // 200,004 B
    int*            cursor = (int*)(ws + 401408);      // 200,000 B
    int*            bsum   = (int*)(ws + 601600);      // 1,024 B
    int*            boff   = (int*)(ws + 602624);      // 1,024 B
    int2*           csr2   = (int2*)(ws + 603648);     // 6,400,000 B
    unsigned short* h_bf   = (unsigned short*)(ws + 7003648);   // 9.6 MB
    float*          xb     = (float*)(ws + 16603648);           // 19.2 MB
    float*          out    = (float*)d_out;

    const int nStrips = NODES / 16;                    // 3125 exact
    const int NB      = (NODES + 255) / 256;           // 196

    hipMemsetAsync(deg, 0, NODES * sizeof(int), stream);
    // h = gelu(x_feat @ W_pre + b_pre) -> bf16 (fp32 read, in-register cvt)
    gemm96_pre<<<512, 256, 0, stream>>>(x_feat, W_pre, b_pre, h_bf, nStrips);
    // CSR build (parallel scan)
    hist_deg<<<(EDGES + 255) / 256, 256, 0, stream>>>(dst, deg);
    deg_block_sum<<<NB, 256, 0, stream>>>(deg, bsum);
    scan_bsum<<<1, 256, 0, stream>>>(bsum, boff, NB);
    scan_expand<<<NB, 256, 0, stream>>>(deg, boff, off, cursor);
    build_csr2<<<(EDGES + 255) / 256, 256, 0, stream>>>(dst, src, cursor, csr2);
    // xb = x_feat + pull-sum(h[src]*bases)
    gather_nodes<<<(NODES * 12 + 255) / 256, 256, 0, stream>>>(
        h_bf, bases, off, csr2, x_feat, xb);
    // out = xb + gelu(gelu(xb@W1+b1)@W2+b2), fused FFN
    gemm96_dual<<<512, 256, 0, stream>>>(xb, W1, b1, W2, b2, out, nStrips);
}

// Round 2
// 569.947 us; speedup vs baseline: 1.2828x; 1.0242x over previous
//
#include <hip/hip_runtime.h>

#define NODES 50000
#define EDGES 800000
#define H 96
#define CAP 64

typedef float floatx4 __attribute__((ext_vector_type(4)));
typedef unsigned short ushort8 __attribute__((ext_vector_type(8)));
typedef __bf16 bf16x8 __attribute__((ext_vector_type(8)));

static __device__ __forceinline__ unsigned short f2b(float f) {
    unsigned int u = __float_as_uint(f);
    u = u + 0x7fffu + ((u >> 16) & 1u);   // RNE
    return (unsigned short)(u >> 16);
}
static __device__ __forceinline__ float b2f(unsigned short u) {
    return __uint_as_float(((unsigned int)u) << 16);
}
static __device__ __forceinline__ float gelu_erf(float x) {
    return 0.5f * x * (1.0f + erff(x * 0.70710678118654752f));
}
static __device__ __forceinline__ bf16x8 pack_bf8(floatx4 a, floatx4 b) {
    union { ushort8 u; bf16x8 v; } r;
    #pragma unroll
    for (int j = 0; j < 4; ++j) { r.u[j] = f2b(a[j]); r.u[4 + j] = f2b(b[j]); }
    return r.v;
}

// ---------------- GEMM 1: h = gelu(x_feat @ W_pre + b) -> bf16 --------------
// Also initializes the padded-CSR cursors and the work-steal counter.
// mfma_f32_16x16x32_bf16: A[m=lane&15][k=quad*8+j]; B[k][n=lane&15];
// C/D col=lane&15, row=quad*4+r (m89/m91-verified).
__global__ __launch_bounds__(256) void gemm96_pre(
    const float* __restrict__ A,
    const float* __restrict__ W,
    const float* __restrict__ bias,
    unsigned short* __restrict__ outp,
    int* __restrict__ cursor,
    int* __restrict__ wctr,
    int nStrips)
{
    const int g = blockIdx.x * 256 + threadIdx.x;
    if (g < NODES) cursor[g] = g * CAP;      // bucket base = end cursor init
    if (g == 0) *wctr = 0;                   // re-init every replay

    __shared__ unsigned short Wt[96][104];  // [n][k] bf16
    const int tid = threadIdx.x;
    #pragma unroll
    for (int j = 0; j < 36; ++j) {          // 9216 = 256*36
        const int f = tid + 256 * j;
        const int k = f / 96, n = f - k * 96;
        Wt[n][k] = f2b(W[f]);
    }
    __syncthreads();

    const int lane = tid & 63;
    const int quad = lane >> 4;
    const int l16  = lane & 15;

    bf16x8 Bf[3][6];
    float  bv[6];
    #pragma unroll
    for (int ks = 0; ks < 3; ++ks)
        #pragma unroll
        for (int nt = 0; nt < 6; ++nt)
            Bf[ks][nt] = *(const bf16x8*)(&Wt[nt * 16 + l16][ks * 32 + quad * 8]);
    #pragma unroll
    for (int nt = 0; nt < 6; ++nt) bv[nt] = bias[nt * 16 + l16];

    const int gwave  = (blockIdx.x * 256 + tid) >> 6;
    const int nWaves = (gridDim.x * 256) >> 6;

    for (int strip = gwave; strip < nStrips; strip += nWaves) {
        const int row0 = strip * 16;
        const float* Ap = A + (size_t)(row0 + l16) * H + quad * 8;

        bf16x8 Af[3];
        #pragma unroll
        for (int ks = 0; ks < 3; ++ks) {
            const floatx4 a0 = *(const floatx4*)(Ap + ks * 32);
            const floatx4 a1 = *(const floatx4*)(Ap + ks * 32 + 4);
            Af[ks] = pack_bf8(a0, a1);
        }

        floatx4 acc[6];
        #pragma unroll
        for (int nt = 0; nt < 6; ++nt) acc[nt] = (floatx4){0.f, 0.f, 0.f, 0.f};
        #pragma unroll
        for (int ks = 0; ks < 3; ++ks)
            #pragma unroll
            for (int nt = 0; nt < 6; ++nt)
                acc[nt] = __builtin_amdgcn_mfma_f32_16x16x32_bf16(Af[ks], Bf[ks][nt], acc[nt], 0, 0, 0);

        #pragma unroll
        for (int nt = 0; nt < 6; ++nt) {
            const int col = nt * 16 + l16;
            #pragma unroll
            for (int r = 0; r < 4; ++r) {
                const int row = row0 + quad * 4 + r;
                outp[(size_t)row * H + col] = f2b(gelu_erf(acc[nt][r] + bv[nt]));
            }
        }
    }
}

// ---------------- padded-bucket CSR scatter ---------------------------------
// cursor[n] pre-set to n*CAP by gemm96_pre; after this pass cursor[n] = end.
__global__ __launch_bounds__(256) void build_csr2(
    const int* __restrict__ dst, const int* __restrict__ src,
    int* __restrict__ cursor, int2* __restrict__ csr)
{
    const int e = blockIdx.x * 256 + threadIdx.x;
    if (e < EDGES) {
        const int d = dst[e];
        const int p = atomicAdd(&cursor[d], 1);
        if (p < d * CAP + CAP) {             // overflow guard (P~0 at deg~16)
            int2 es; es.x = e; es.y = src[e];
            csr[p] = es;
        }
    }
}

// ---------------- Fused: aggregate + residual + dual-FFN --------------------
// Per wave: strip of 16 nodes. Gather phase (4 lanes/node x 24 feats) builds
// xb = x_feat + sum(h[src]*bases) in a per-wave LDS fp32 tile; then both MFMA
// stages + residual run from LDS. xb never touches HBM. No barriers needed
// after weight staging (same-wave DS ordering). Work-stealing over strips.
__global__ __launch_bounds__(256, 2) void gather_ffn(
    const unsigned short* __restrict__ h,
    const float* __restrict__ bases,
    const int2* __restrict__ csr,
    const int* __restrict__ cursor,
    const float* __restrict__ x_feat,
    const float* __restrict__ W1, const float* __restrict__ b1,
    const float* __restrict__ W2, const float* __restrict__ b2,
    float* __restrict__ outp,
    int* __restrict__ wctr,
    int nStrips)
{
    __shared__ unsigned short Wt1[96][104];   // [n][k] bf16
    __shared__ unsigned short Wt2[96][104];
    __shared__ float          Xb[4][16][100]; // per-wave xb tile, pad 100 (2-way banks)
    __shared__ unsigned short Tt[4][16][120]; // per-wave t tile

    const int tid = threadIdx.x;
    #pragma unroll
    for (int j = 0; j < 36; ++j) {
        const int f = tid + 256 * j;
        const int k = f / 96, n = f - k * 96;
        Wt1[n][k] = f2b(W1[f]);
        Wt2[n][k] = f2b(W2[f]);
    }
    __syncthreads();

    const int lane = tid & 63;
    const int quad = lane >> 4;
    const int l16  = lane & 15;
    const int w    = tid >> 6;
    const int nd   = lane >> 2;               // node within strip 0..15
    const int seg  = lane & 3;                // feature chunk 0..3 (24 each)
    const int c0   = seg * 24;

    float bv1[6], bv2[6];
    #pragma unroll
    for (int nt = 0; nt < 6; ++nt) {
        bv1[nt] = b1[nt * 16 + l16];
        bv2[nt] = b2[nt * 16 + l16];
    }

    for (;;) {
        int s;
        if (lane == 0) s = atomicAdd(wctr, 1);
        s = __shfl(s, 0);
        if (s >= nStrips) break;
        const int row0 = s * 16;

        // ---- gather: xb chunk in registers
        const int node = row0 + nd;
        const int i0 = node * CAP;
        const int i1 = cursor[node];

        float acc[24];
        #pragma unroll
        for (int j = 0; j < 24; ++j) acc[j] = 0.f;
        for (int i = i0; i < i1; ++i) {
            const int2 es = csr[i];
            const float* bp = bases + (size_t)es.x * H + c0;
            const unsigned short* hp = h + (size_t)es.y * H + c0;
            floatx4 b[6]; ushort8 hv[3];
            #pragma unroll
            for (int j = 0; j < 6; ++j) b[j] = *(const floatx4*)(bp + 4 * j);
            #pragma unroll
            for (int j = 0; j < 3; ++j) hv[j] = *(const ushort8*)(hp + 8 * j);
            #pragma unroll
            for (int j = 0; j < 24; ++j)
                acc[j] = fmaf(b[j >> 2][j & 3], b2f(hv[j >> 3][j & 7]), acc[j]);
        }
        const float* xp = x_feat + (size_t)node * H + c0;
        #pragma unroll
        for (int j = 0; j < 6; ++j) {
            const floatx4 xv = *(const floatx4*)(xp + 4 * j);
            #pragma unroll
            for (int t = 0; t < 4; ++t) acc[4 * j + t] += xv[t];
        }
        #pragma unroll
        for (int j = 0; j < 6; ++j) {
            floatx4 v;
            #pragma unroll
            for (int t = 0; t < 4; ++t) v[t] = acc[4 * j + t];
            *(floatx4*)(&Xb[w][nd][c0 + 4 * j]) = v;
        }

        // ---- stage 1: t = gelu(xb @ W1 + b1)   (A from Xb LDS, B from Wt1)
        bf16x8 Af[3];
        #pragma unroll
        for (int ks = 0; ks < 3; ++ks) {
            const floatx4 a0 = *(const floatx4*)(&Xb[w][l16][ks * 32 + quad * 8]);
            const floatx4 a1 = *(const floatx4*)(&Xb[w][l16][ks * 32 + quad * 8 + 4]);
            Af[ks] = pack_bf8(a0, a1);
        }
        floatx4 facc[6];
        #pragma unroll
        for (int nt = 0; nt < 6; ++nt) facc[nt] = (floatx4){0.f, 0.f, 0.f, 0.f};
        #pragma unroll
        for (int ks = 0; ks < 3; ++ks)
            #pragma unroll
            for (int nt = 0; nt < 6; ++nt) {
                const bf16x8 Bf1 = *(const bf16x8*)(&Wt1[nt * 16 + l16][ks * 32 + quad * 8]);
                facc[nt] = __builtin_amdgcn_mfma_f32_16x16x32_bf16(Af[ks], Bf1, facc[nt], 0, 0, 0);
            }
        #pragma unroll
        for (int nt = 0; nt < 6; ++nt)
            #pragma unroll
            for (int r = 0; r < 4; ++r)
                Tt[w][quad * 4 + r][nt * 16 + l16] = f2b(gelu_erf(facc[nt][r] + bv1[nt]));

        // ---- stage 2: out = xb + gelu(t @ W2 + b2)
        bf16x8 Tf[3];
        #pragma unroll
        for (int ks = 0; ks < 3; ++ks)
            Tf[ks] = *(const bf16x8*)(&Tt[w][l16][ks * 32 + quad * 8]);
        #pragma unroll
        for (int nt = 0; nt < 6; ++nt) facc[nt] = (floatx4){0.f, 0.f, 0.f, 0.f};
        #pragma unroll
        for (int ks = 0; ks < 3; ++ks)
            #pragma unroll
            for (int nt = 0; nt < 6; ++nt) {
                const bf16x8 Bf2 = *(const bf16x8*)(&Wt2[nt * 16 + l16][ks * 32 + quad * 8]);
                facc[nt] = __builtin_amdgcn_mfma_f32_16x16x32_bf16(Tf[ks], Bf2, facc[nt], 0, 0, 0);
            }
        #pragma unroll
        for (int nt = 0; nt < 6; ++nt) {
            const int col = nt * 16 + l16;
            #pragma unroll
            for (int r = 0; r < 4; ++r) {
                const int row = row0 + quad * 4 + r;
                outp[(size_t)row * H + col] = Xb[w][quad * 4 + r][col]
                                            + gelu_erf(facc[nt][r] + bv2[nt]);
            }
        }
    }
}

extern "C" void kernel_launch(void* const* d_in, const int* in_sizes, int n_in,
                              void* d_out, int out_size, void* d_ws, size_t ws_size,
                              hipStream_t stream)
{
    const float* x_feat = (const float*)d_in[0];
    const float* bases  = (const float*)d_in[1];
    const float* W_pre  = (const float*)d_in[2];
    const float* b_pre  = (const float*)d_in[3];
    const float* W1     = (const float*)d_in[4];
    const float* b1     = (const float*)d_in[5];
    const float* W2     = (const float*)d_in[6];
    const float* b2     = (const float*)d_in[7];
    const int* src = (const int*)d_in[8];
    const int* dst = (const int*)d_in[9];

    char* ws = (char*)d_ws;
    int*            cursor = (int*)(ws);                       // 200,000 B
    int*            wctr   = (int*)(ws + 200704);              // 4 B
    int2*           csr2   = (int2*)(ws + 1048576);            // 25,600,000 B
    unsigned short* h_bf   = (unsigned short*)(ws + 27262976); // 9,600,000 B
    float*          out    = (float*)d_out;

    const int nStrips = NODES / 16;                            // 3125 exact

    // h = gelu(x_feat @ W_pre + b_pre) -> bf16; also init cursor + wctr
    gemm96_pre<<<512, 256, 0, stream>>>(x_feat, W_pre, b_pre, h_bf, cursor, wctr, nStrips);
    // padded-bucket CSR scatter
    build_csr2<<<(EDGES + 255) / 256, 256, 0, stream>>>(dst, src, cursor, csr2);
    // out = xb + gelu(gelu(xb@W1+b1)@W2+b2), xb built in LDS per strip
    gather_ffn<<<512, 256, 0, stream>>>(
        h_bf, bases, csr2, cursor, x_feat, W1, b1, W2, b2, out, wctr, nStrips);
}

// Round 3
// 557.742 us; speedup vs baseline: 1.3109x; 1.0219x over previous
//
#include <hip/hip_runtime.h>

#define NODES 50000
#define EDGES 800000
#define H 96
#define CAP 64

typedef float floatx4 __attribute__((ext_vector_type(4)));
typedef unsigned short ushort8 __attribute__((ext_vector_type(8)));
typedef __bf16 bf16x8 __attribute__((ext_vector_type(8)));

static __device__ __forceinline__ unsigned short f2b(float f) {
    unsigned int u = __float_as_uint(f);
    u = u + 0x7fffu + ((u >> 16) & 1u);   // RNE
    return (unsigned short)(u >> 16);
}
static __device__ __forceinline__ float b2f(unsigned short u) {
    return __uint_as_float(((unsigned int)u) << 16);
}
static __device__ __forceinline__ float gelu_erf(float x) {
    return 0.5f * x * (1.0f + erff(x * 0.70710678118654752f));
}
static __device__ __forceinline__ bf16x8 pack_bf8(const float* a) {
    union { ushort8 u; bf16x8 v; } r;
    #pragma unroll
    for (int j = 0; j < 8; ++j) r.u[j] = f2b(a[j]);
    return r.v;
}
static __device__ __forceinline__ floatx4 vec4(const float* a) {
    floatx4 v;
    #pragma unroll
    for (int j = 0; j < 4; ++j) v[j] = a[j];
    return v;
}

// ---------------- GEMM 1: h = gelu(x_feat @ W_pre + b) -> bf16 --------------
// Also initializes the padded-CSR cursors and the work-steal counter.
// mfma_f32_16x16x32_bf16: A[m=lane&15][k=quad*8+j]; B[k][n=lane&15];
// C/D col=lane&15, row=quad*4+r (m89/m91-verified).
__global__ __launch_bounds__(256) void gemm96_pre(
    const float* __restrict__ A,
    const float* __restrict__ W,
    const float* __restrict__ bias,
    unsigned short* __restrict__ outp,
    int* __restrict__ cursor,
    int* __restrict__ wctr,
    int nStrips)
{
    const int g = blockIdx.x * 256 + threadIdx.x;
    if (g < NODES) cursor[g] = g * CAP;      // bucket base cursor init
    if (g == 0) *wctr = 0;                   // re-init every replay

    __shared__ unsigned short Wt[96][104];  // [n][k] bf16
    const int tid = threadIdx.x;
    #pragma unroll
    for (int j = 0; j < 36; ++j) {          // 9216 = 256*36
        const int f = tid + 256 * j;
        const int k = f / 96, n = f - k * 96;
        Wt[n][k] = f2b(W[f]);
    }
    __syncthreads();

    const int lane = tid & 63;
    const int quad = lane >> 4;
    const int l16  = lane & 15;

    bf16x8 Bf[3][6];
    float  bv[6];
    #pragma unroll
    for (int ks = 0; ks < 3; ++ks)
        #pragma unroll
        for (int nt = 0; nt < 6; ++nt)
            Bf[ks][nt] = *(const bf16x8*)(&Wt[nt * 16 + l16][ks * 32 + quad * 8]);
    #pragma unroll
    for (int nt = 0; nt < 6; ++nt) bv[nt] = bias[nt * 16 + l16];

    const int gwave  = (blockIdx.x * 256 + tid) >> 6;
    const int nWaves = (gridDim.x * 256) >> 6;

    for (int strip = gwave; strip < nStrips; strip += nWaves) {
        const int row0 = strip * 16;
        const float* Ap = A + (size_t)(row0 + l16) * H + quad * 8;

        bf16x8 Af[3];
        #pragma unroll
        for (int ks = 0; ks < 3; ++ks) {
            float tmp[8];
            const floatx4 a0 = *(const floatx4*)(Ap + ks * 32);
            const floatx4 a1 = *(const floatx4*)(Ap + ks * 32 + 4);
            #pragma unroll
            for (int j = 0; j < 4; ++j) { tmp[j] = a0[j]; tmp[4 + j] = a1[j]; }
            Af[ks] = pack_bf8(tmp);
        }

        floatx4 acc[6];
        #pragma unroll
        for (int nt = 0; nt < 6; ++nt) acc[nt] = (floatx4){0.f, 0.f, 0.f, 0.f};
        #pragma unroll
        for (int ks = 0; ks < 3; ++ks)
            #pragma unroll
            for (int nt = 0; nt < 6; ++nt)
                acc[nt] = __builtin_amdgcn_mfma_f32_16x16x32_bf16(Af[ks], Bf[ks][nt], acc[nt], 0, 0, 0);

        #pragma unroll
        for (int nt = 0; nt < 6; ++nt) {
            const int col = nt * 16 + l16;
            #pragma unroll
            for (int r = 0; r < 4; ++r) {
                const int row = row0 + quad * 4 + r;
                outp[(size_t)row * H + col] = f2b(gelu_erf(acc[nt][r] + bv[nt]));
            }
        }
    }
}

// ---------------- padded-bucket CSR scatter ---------------------------------
__global__ __launch_bounds__(256) void build_csr2(
    const int* __restrict__ dst, const int* __restrict__ src,
    int* __restrict__ cursor, int2* __restrict__ csr)
{
    const int e = blockIdx.x * 256 + threadIdx.x;
    if (e < EDGES) {
        const int d = dst[e];
        const int p = atomicAdd(&cursor[d], 1);
        if (p < d * CAP + CAP) {             // overflow guard (P~0 at deg~16)
            int2 es; es.x = e; es.y = src[e];
            csr[p] = es;
        }
    }
}

// ---------------- Fused: aggregate + residual + dual-FFN --------------------
// Gather layout == MFMA A-frag layout: lane (quad,l16) owns node row0+l16,
// features {ks*32+quad*8+j} -> acc regs feed MFMA directly (no Xb tile).
// Residual (fp32, C-layout) and t (bf16, A-layout) redistribute through ONE
// 3584 B/wave scratch, time-multiplexed (same-wave in-order LDS, no barriers).
// LDS = 39,936 (Wt1+Wt2) + 14,336 (scratch) = 54,272 -> 3 blocks/CU.
__global__ __launch_bounds__(256, 3) void gather_ffn(
    const unsigned short* __restrict__ h,
    const float* __restrict__ bases,
    const int2* __restrict__ csr,
    const int* __restrict__ cursor,
    const float* __restrict__ x_feat,
    const float* __restrict__ W1, const float* __restrict__ b1,
    const float* __restrict__ W2, const float* __restrict__ b2,
    float* __restrict__ outp,
    int* __restrict__ wctr,
    int nStrips)
{
    __shared__ unsigned short Wt1[96][104];   // [n][k] bf16
    __shared__ unsigned short Wt2[96][104];
    __shared__ __align__(16) char Scr[4][3584]; // per-wave scratch

    const int tid = threadIdx.x;
    #pragma unroll
    for (int j = 0; j < 36; ++j) {
        const int f = tid + 256 * j;
        const int k = f / 96, n = f - k * 96;
        Wt1[n][k] = f2b(W1[f]);
        Wt2[n][k] = f2b(W2[f]);
    }
    __syncthreads();

    const int lane = tid & 63;
    const int quad = lane >> 4;
    const int l16  = lane & 15;
    const int w    = tid >> 6;
    float*          Sf = (float*)Scr[w];          // view [16][52] fp32
    unsigned short* St = (unsigned short*)Scr[w]; // view [16][112] bf16

    float bv1[6], bv2[6];
    #pragma unroll
    for (int nt = 0; nt < 6; ++nt) {
        bv1[nt] = b1[nt * 16 + l16];
        bv2[nt] = b2[nt * 16 + l16];
    }

    const int wsw = quad << 3;                // t-scratch write swizzle
    const int rsw = ((l16 >> 2) & 3) << 3;    // t-scratch read swizzle

    for (;;) {
        int s;
        if (lane == 0) s = atomicAdd(wctr, 1);
        s = __shfl(s, 0);
        if (s >= nStrips) break;
        const int row0 = s * 16;

        // ---- gather: acc[ks*8+j] = aggr for node row0+l16, col ks*32+quad*8+j
        const int node = row0 + l16;
        const int i0 = node * CAP;
        int i1 = cursor[node];
        i1 = min(i1, i0 + CAP);

        float acc[24];
        #pragma unroll
        for (int j = 0; j < 24; ++j) acc[j] = 0.f;

        int i = i0;
        for (; i + 1 < i1; i += 2) {          // 2 edges in flight (MLP x2)
            const int2 ea = csr[i];
            const int2 eb = csr[i + 1];
            const float* bpa = bases + (size_t)ea.x * H + quad * 8;
            const float* bpb = bases + (size_t)eb.x * H + quad * 8;
            const unsigned short* hpa = h + (size_t)ea.y * H + quad * 8;
            const unsigned short* hpb = h + (size_t)eb.y * H + quad * 8;
            floatx4 ba[6], bb[6]; ushort8 hva[3], hvb[3];
            #pragma unroll
            for (int ks = 0; ks < 3; ++ks) {
                ba[2*ks]   = *(const floatx4*)(bpa + ks * 32);
                ba[2*ks+1] = *(const floatx4*)(bpa + ks * 32 + 4);
                hva[ks]    = *(const ushort8*)(hpa + ks * 32);
                bb[2*ks]   = *(const floatx4*)(bpb + ks * 32);
                bb[2*ks+1] = *(const floatx4*)(bpb + ks * 32 + 4);
                hvb[ks]    = *(const ushort8*)(hpb + ks * 32);
            }
            #pragma unroll
            for (int ks = 0; ks < 3; ++ks)
                #pragma unroll
                for (int j = 0; j < 8; ++j) {
                    acc[ks*8+j] = fmaf(ba[2*ks + (j>>2)][j&3], b2f(hva[ks][j]), acc[ks*8+j]);
                    acc[ks*8+j] = fmaf(bb[2*ks + (j>>2)][j&3], b2f(hvb[ks][j]), acc[ks*8+j]);
                }
        }
        if (i < i1) {                          // odd remainder
            const int2 ea = csr[i];
            const float* bpa = bases + (size_t)ea.x * H + quad * 8;
            const unsigned short* hpa = h + (size_t)ea.y * H + quad * 8;
            #pragma unroll
            for (int ks = 0; ks < 3; ++ks) {
                const floatx4 b0 = *(const floatx4*)(bpa + ks * 32);
                const floatx4 b1v = *(const floatx4*)(bpa + ks * 32 + 4);
                const ushort8 hv = *(const ushort8*)(hpa + ks * 32);
                #pragma unroll
                for (int j = 0; j < 4; ++j) {
                    acc[ks*8+j]   = fmaf(b0[j],  b2f(hv[j]),     acc[ks*8+j]);
                    acc[ks*8+4+j] = fmaf(b1v[j], b2f(hv[4+j]),   acc[ks*8+4+j]);
                }
            }
        }

        // ---- + x_feat (residual 1): xb in regs, A-fragment layout
        const float* xp = x_feat + (size_t)node * H + quad * 8;
        #pragma unroll
        for (int ks = 0; ks < 3; ++ks) {
            const floatx4 x0 = *(const floatx4*)(xp + ks * 32);
            const floatx4 x1 = *(const floatx4*)(xp + ks * 32 + 4);
            #pragma unroll
            for (int j = 0; j < 4; ++j) {
                acc[ks*8+j]   += x0[j];
                acc[ks*8+4+j] += x1[j];
            }
        }

        // ---- residual redistribution A-layout -> C-layout via Sf halves
        // half A: cols [0,48)
        *(floatx4*)&Sf[l16 * 52 + quad * 8]     = vec4(&acc[0]);
        *(floatx4*)&Sf[l16 * 52 + quad * 8 + 4] = vec4(&acc[4]);
        if (quad < 2) {
            *(floatx4*)&Sf[l16 * 52 + 32 + quad * 8]     = vec4(&acc[8]);
            *(floatx4*)&Sf[l16 * 52 + 32 + quad * 8 + 4] = vec4(&acc[12]);
        }
        float res[24];
        #pragma unroll
        for (int nt = 0; nt < 3; ++nt)
            #pragma unroll
            for (int r = 0; r < 4; ++r)
                res[nt*4+r] = Sf[(quad*4+r) * 52 + nt*16 + l16];
        // half B: cols [48,96) stored at col-48 (in-order LDS => safe reuse)
        if (quad >= 2) {
            *(floatx4*)&Sf[l16 * 52 + (quad-2) * 8]     = vec4(&acc[8]);
            *(floatx4*)&Sf[l16 * 52 + (quad-2) * 8 + 4] = vec4(&acc[12]);
        }
        *(floatx4*)&Sf[l16 * 52 + 16 + quad * 8]     = vec4(&acc[16]);
        *(floatx4*)&Sf[l16 * 52 + 16 + quad * 8 + 4] = vec4(&acc[20]);
        #pragma unroll
        for (int nt = 3; nt < 6; ++nt)
            #pragma unroll
            for (int r = 0; r < 4; ++r)
                res[nt*4+r] = Sf[(quad*4+r) * 52 + nt*16 + l16 - 48];

        // ---- stage 1: t = gelu(xb @ W1 + b1), A-frags straight from acc
        bf16x8 Af[3];
        #pragma unroll
        for (int ks = 0; ks < 3; ++ks) Af[ks] = pack_bf8(&acc[ks * 8]);
        floatx4 facc[6];
        #pragma unroll
        for (int nt = 0; nt < 6; ++nt) facc[nt] = (floatx4){0.f, 0.f, 0.f, 0.f};
        #pragma unroll
        for (int ks = 0; ks < 3; ++ks)
            #pragma unroll
            for (int nt = 0; nt < 6; ++nt) {
                const bf16x8 Bf1 = *(const bf16x8*)(&Wt1[nt * 16 + l16][ks * 32 + quad * 8]);
                facc[nt] = __builtin_amdgcn_mfma_f32_16x16x32_bf16(Af[ks], Bf1, facc[nt], 0, 0, 0);
            }

        // ---- t C-layout -> A-layout via St (XOR-swizzled, overwrites Sf)
        #pragma unroll
        for (int nt = 0; nt < 6; ++nt)
            #pragma unroll
            for (int r = 0; r < 4; ++r)
                St[(quad*4+r) * 112 + ((nt*16 + l16) ^ wsw)] =
                    f2b(gelu_erf(facc[nt][r] + bv1[nt]));
        bf16x8 Tf[3];
        #pragma unroll
        for (int ks = 0; ks < 3; ++ks)
            Tf[ks] = *(const bf16x8*)(&St[l16 * 112 + ((ks*32 + quad*8) ^ rsw)]);

        // ---- stage 2: out = xb + gelu(t @ W2 + b2)
        #pragma unroll
        for (int nt = 0; nt < 6; ++nt) facc[nt] = (floatx4){0.f, 0.f, 0.f, 0.f};
        #pragma unroll
        for (int ks = 0; ks < 3; ++ks)
            #pragma unroll
            for (int nt = 0; nt < 6; ++nt) {
                const bf16x8 Bf2 = *(const bf16x8*)(&Wt2[nt * 16 + l16][ks * 32 + quad * 8]);
                facc[nt] = __builtin_amdgcn_mfma_f32_16x16x32_bf16(Tf[ks], Bf2, facc[nt], 0, 0, 0);
            }
        #pragma unroll
        for (int nt = 0; nt < 6; ++nt) {
            const int col = nt * 16 + l16;
            #pragma unroll
            for (int r = 0; r < 4; ++r) {
                const int row = row0 + quad * 4 + r;
                outp[(size_t)row * H + col] = res[nt*4+r] + gelu_erf(facc[nt][r] + bv2[nt]);
            }
        }
    }
}

extern "C" void kernel_launch(void* const* d_in, const int* in_sizes, int n_in,
                              void* d_out, int out_size, void* d_ws, size_t ws_size,
                              hipStream_t stream)
{
    const float* x_feat = (const float*)d_in[0];
    const float* bases  = (const float*)d_in[1];
    const float* W_pre  = (const float*)d_in[2];
    const float* b_pre  = (const float*)d_in[3];
    const float* W1     = (const float*)d_in[4];
    const float* b1     = (const float*)d_in[5];
    const float* W2     = (const float*)d_in[6];
    const float* b2     = (const float*)d_in[7];
    const int* src = (const int*)d_in[8];
    const int* dst = (const int*)d_in[9];

    char* ws = (char*)d_ws;
    int*            cursor = (int*)(ws);                       // 200,000 B
    int*            wctr   = (int*)(ws + 200704);              // 4 B
    int2*           csr2   = (int2*)(ws + 1048576);            // 25,600,000 B
    unsigned short* h_bf   = (unsigned short*)(ws + 27262976); // 9,600,000 B
    float*          out    = (float*)d_out;

    const int nStrips = NODES / 16;                            // 3125 exact

    // h = gelu(x_feat @ W_pre + b_pre) -> bf16; also init cursor + wctr
    gemm96_pre<<<512, 256, 0, stream>>>(x_feat, W_pre, b_pre, h_bf, cursor, wctr, nStrips);
    // padded-bucket CSR scatter
    build_csr2<<<(EDGES + 255) / 256, 256, 0, stream>>>(dst, src, cursor, csr2);
    // out = xb + gelu(gelu(xb@W1+b1)@W2+b2), all-register/LDS-scratch fused
    gather_ffn<<<768, 256, 0, stream>>>(
        h_bf, bases, csr2, cursor, x_feat, W1, b1, W2, b2, out, wctr, nStrips);
}

// Round 4
// 535.120 us; speedup vs baseline: 1.3663x; 1.0423x over previous
//
#include <hip/hip_runtime.h>

#define NODES 50000
#define EDGES 800000
#define H 96
#define CAP 64

typedef float floatx4 __attribute__((ext_vector_type(4)));
typedef unsigned short ushort8 __attribute__((ext_vector_type(8)));
typedef __bf16 bf16x8 __attribute__((ext_vector_type(8)));

static __device__ __forceinline__ unsigned short f2b(float f) {
    unsigned int u = __float_as_uint(f);
    u = u + 0x7fffu + ((u >> 16) & 1u);   // RNE
    return (unsigned short)(u >> 16);
}
static __device__ __forceinline__ float b2f(unsigned short u) {
    return __uint_as_float(((unsigned int)u) << 16);
}
static __device__ __forceinline__ float gelu_erf(float x) {
    return 0.5f * x * (1.0f + erff(x * 0.70710678118654752f));
}
static __device__ __forceinline__ bf16x8 pack_bf8(const float* a) {
    union { ushort8 u; bf16x8 v; } r;
    #pragma unroll
    for (int j = 0; j < 8; ++j) r.u[j] = f2b(a[j]);
    return r.v;
}

// ---------------- GEMM 1: h = gelu(x_feat @ W_pre + b) -> bf16 --------------
// Also initializes the padded-CSR cursors.
// mfma_f32_16x16x32_bf16: A[m=lane&15][k=quad*8+j]; B[k][n=lane&15];
// C/D col=lane&15, row=quad*4+r (m89/m91-verified).
__global__ __launch_bounds__(256) void gemm96_pre(
    const float* __restrict__ A,
    const float* __restrict__ W,
    const float* __restrict__ bias,
    unsigned short* __restrict__ outp,
    int* __restrict__ cursor,
    int nStrips)
{
    const int g = blockIdx.x * 256 + threadIdx.x;
    if (g < NODES) cursor[g] = g * CAP;      // bucket base cursor init

    __shared__ unsigned short Wt[96][104];  // [n][k] bf16
    const int tid = threadIdx.x;
    #pragma unroll
    for (int j = 0; j < 36; ++j) {          // 9216 = 256*36
        const int f = tid + 256 * j;
        const int k = f / 96, n = f - k * 96;
        Wt[n][k] = f2b(W[f]);
    }
    __syncthreads();

    const int lane = tid & 63;
    const int quad = lane >> 4;
    const int l16  = lane & 15;

    bf16x8 Bf[3][6];
    float  bv[6];
    #pragma unroll
    for (int ks = 0; ks < 3; ++ks)
        #pragma unroll
        for (int nt = 0; nt < 6; ++nt)
            Bf[ks][nt] = *(const bf16x8*)(&Wt[nt * 16 + l16][ks * 32 + quad * 8]);
    #pragma unroll
    for (int nt = 0; nt < 6; ++nt) bv[nt] = bias[nt * 16 + l16];

    const int gwave  = (blockIdx.x * 256 + tid) >> 6;
    const int nWaves = (gridDim.x * 256) >> 6;

    for (int strip = gwave; strip < nStrips; strip += nWaves) {
        const int row0 = strip * 16;
        const float* Ap = A + (size_t)(row0 + l16) * H + quad * 8;

        bf16x8 Af[3];
        #pragma unroll
        for (int ks = 0; ks < 3; ++ks) {
            float tmp[8];
            const floatx4 a0 = *(const floatx4*)(Ap + ks * 32);
            const floatx4 a1 = *(const floatx4*)(Ap + ks * 32 + 4);
            #pragma unroll
            for (int j = 0; j < 4; ++j) { tmp[j] = a0[j]; tmp[4 + j] = a1[j]; }
            Af[ks] = pack_bf8(tmp);
        }

        floatx4 acc[6];
        #pragma unroll
        for (int nt = 0; nt < 6; ++nt) acc[nt] = (floatx4){0.f, 0.f, 0.f, 0.f};
        #pragma unroll
        for (int ks = 0; ks < 3; ++ks)
            #pragma unroll
            for (int nt = 0; nt < 6; ++nt)
                acc[nt] = __builtin_amdgcn_mfma_f32_16x16x32_bf16(Af[ks], Bf[ks][nt], acc[nt], 0, 0, 0);

        #pragma unroll
        for (int nt = 0; nt < 6; ++nt) {
            const int col = nt * 16 + l16;
            #pragma unroll
            for (int r = 0; r < 4; ++r) {
                const int row = row0 + quad * 4 + r;
                outp[(size_t)row * H + col] = f2b(gelu_erf(acc[nt][r] + bv[nt]));
            }
        }
    }
}

// ---------------- padded-bucket CSR scatter ---------------------------------
__global__ __launch_bounds__(256) void build_csr2(
    const int* __restrict__ dst, const int* __restrict__ src,
    int* __restrict__ cursor, int2* __restrict__ csr)
{
    const int e = blockIdx.x * 256 + threadIdx.x;
    if (e < EDGES) {
        const int d = dst[e];
        const int p = atomicAdd(&cursor[d], 1);
        if (p < d * CAP + CAP) {             // overflow guard (P~0 at deg~16)
            int2 es; es.x = e; es.y = src[e];
            csr[p] = es;
        }
    }
}

// ---------------- Pull-aggregate + residual: xb = x_feat + sum --------------
// Latency-bound kernel => maximize TLP: zero LDS, VGPR<=64 (8 waves/SIMD),
// 12 threads/node x 8 feats, edge loop unrolled x2 for MLP.
__global__ __launch_bounds__(256, 8) void gather_nodes(
    const unsigned short* __restrict__ h,
    const float* __restrict__ bases,
    const int2* __restrict__ csr,
    const int* __restrict__ cursor,
    const float* __restrict__ x_feat,
    float* __restrict__ xb)
{
    const int t = blockIdx.x * 256 + threadIdx.x;
    const int n = t / 12;
    if (n >= NODES) return;
    const int seg = t - n * 12;
    const int so8 = seg * 8;
    const int i0 = n * CAP;
    const int i1 = min(cursor[n], i0 + CAP);

    floatx4 acc0 = (floatx4){0.f, 0.f, 0.f, 0.f};
    floatx4 acc1 = (floatx4){0.f, 0.f, 0.f, 0.f};

    int i = i0;
    for (; i + 1 < i1; i += 2) {          // 2 independent edges in flight
        const int2 ea = csr[i];
        const int2 eb = csr[i + 1];
        const size_t eoa = (size_t)ea.x * H + so8;
        const size_t eob = (size_t)eb.x * H + so8;
        const floatx4 ba0 = *(const floatx4*)(bases + eoa);
        const floatx4 ba1 = *(const floatx4*)(bases + eoa + 4);
        const ushort8 hva = *(const ushort8*)(h + (size_t)ea.y * H + so8);
        const floatx4 bb0 = *(const floatx4*)(bases + eob);
        const floatx4 bb1 = *(const floatx4*)(bases + eob + 4);
        const ushort8 hvb = *(const ushort8*)(h + (size_t)eb.y * H + so8);
        #pragma unroll
        for (int j = 0; j < 4; ++j) {
            acc0[j] = fmaf(ba0[j], b2f(hva[j]),     acc0[j]);
            acc1[j] = fmaf(ba1[j], b2f(hva[4 + j]), acc1[j]);
        }
        #pragma unroll
        for (int j = 0; j < 4; ++j) {
            acc0[j] = fmaf(bb0[j], b2f(hvb[j]),     acc0[j]);
            acc1[j] = fmaf(bb1[j], b2f(hvb[4 + j]), acc1[j]);
        }
    }
    if (i < i1) {                          // odd remainder
        const int2 ea = csr[i];
        const size_t eoa = (size_t)ea.x * H + so8;
        const floatx4 ba0 = *(const floatx4*)(bases + eoa);
        const floatx4 ba1 = *(const floatx4*)(bases + eoa + 4);
        const ushort8 hva = *(const ushort8*)(h + (size_t)ea.y * H + so8);
        #pragma unroll
        for (int j = 0; j < 4; ++j) {
            acc0[j] = fmaf(ba0[j], b2f(hva[j]),     acc0[j]);
            acc1[j] = fmaf(ba1[j], b2f(hva[4 + j]), acc1[j]);
        }
    }

    const size_t no = (size_t)n * H + so8;
    const floatx4 x0 = *(const floatx4*)(x_feat + no);
    const floatx4 x1 = *(const floatx4*)(x_feat + no + 4);
    #pragma unroll
    for (int j = 0; j < 4; ++j) { acc0[j] += x0[j]; acc1[j] += x1[j]; }
    *(floatx4*)(xb + no)     = acc0;
    *(floatx4*)(xb + no + 4) = acc1;
}

// ---------------- Fused FFN: out = xb + gelu(gelu(xb@W1+b1)@W2+b2) ----------
// A read fp32 + in-reg bf16 cvt; t redistributed C->A layout through a
// per-wave XOR-swizzled LDS scratch (same-wave in-order DS, no barriers).
// Residual read directly from xb (C-layout, coalesced, L2/L3-hot).
__global__ __launch_bounds__(256) void ffn_dual(
    const float* __restrict__ A,        // xb fp32 [N][96]
    const float* __restrict__ W1, const float* __restrict__ b1,
    const float* __restrict__ W2, const float* __restrict__ b2,
    float* __restrict__ outp,
    int nStrips)
{
    __shared__ unsigned short Wt1[96][104];   // [n][k] bf16
    __shared__ unsigned short Wt2[96][104];
    __shared__ unsigned short St[4][16][112]; // per-wave t scratch (swizzled)

    const int tid = threadIdx.x;
    #pragma unroll
    for (int j = 0; j < 36; ++j) {
        const int f = tid + 256 * j;
        const int k = f / 96, n = f - k * 96;
        Wt1[n][k] = f2b(W1[f]);
        Wt2[n][k] = f2b(W2[f]);
    }
    __syncthreads();

    const int lane = tid & 63;
    const int quad = lane >> 4;
    const int l16  = lane & 15;
    const int w    = tid >> 6;

    float bv1[6], bv2[6];
    #pragma unroll
    for (int nt = 0; nt < 6; ++nt) {
        bv1[nt] = b1[nt * 16 + l16];
        bv2[nt] = b2[nt * 16 + l16];
    }

    const int wsw = quad << 3;                // write swizzle (validated R3)
    const int rsw = (l16 >> 2) << 3;          // read swizzle

    const int gwave  = (blockIdx.x * 256 + tid) >> 6;
    const int nWaves = (gridDim.x * 256) >> 6;

    for (int strip = gwave; strip < nStrips; strip += nWaves) {
        const int row0 = strip * 16;
        const float* Ap = A + (size_t)(row0 + l16) * H + quad * 8;

        // ---- stage 1: t = gelu(xb @ W1 + b1)
        bf16x8 Af[3];
        #pragma unroll
        for (int ks = 0; ks < 3; ++ks) {
            float tmp[8];
            const floatx4 a0 = *(const floatx4*)(Ap + ks * 32);
            const floatx4 a1 = *(const floatx4*)(Ap + ks * 32 + 4);
            #pragma unroll
            for (int j = 0; j < 4; ++j) { tmp[j] = a0[j]; tmp[4 + j] = a1[j]; }
            Af[ks] = pack_bf8(tmp);
        }
        floatx4 facc[6];
        #pragma unroll
        for (int nt = 0; nt < 6; ++nt) facc[nt] = (floatx4){0.f, 0.f, 0.f, 0.f};
        #pragma unroll
        for (int ks = 0; ks < 3; ++ks)
            #pragma unroll
            for (int nt = 0; nt < 6; ++nt) {
                const bf16x8 Bf1 = *(const bf16x8*)(&Wt1[nt * 16 + l16][ks * 32 + quad * 8]);
                facc[nt] = __builtin_amdgcn_mfma_f32_16x16x32_bf16(Af[ks], Bf1, facc[nt], 0, 0, 0);
            }

        // ---- t C-layout -> A-layout via per-wave swizzled scratch
        #pragma unroll
        for (int nt = 0; nt < 6; ++nt)
            #pragma unroll
            for (int r = 0; r < 4; ++r)
                St[w][quad * 4 + r][(nt * 16 + l16) ^ wsw] =
                    f2b(gelu_erf(facc[nt][r] + bv1[nt]));
        bf16x8 Tf[3];
        #pragma unroll
        for (int ks = 0; ks < 3; ++ks)
            Tf[ks] = *(const bf16x8*)(&St[w][l16][(ks * 32 + quad * 8) ^ rsw]);

        // ---- stage 2: out = xb + gelu(t @ W2 + b2)
        #pragma unroll
        for (int nt = 0; nt < 6; ++nt) facc[nt] = (floatx4){0.f, 0.f, 0.f, 0.f};
        #pragma unroll
        for (int ks = 0; ks < 3; ++ks)
            #pragma unroll
            for (int nt = 0; nt < 6; ++nt) {
                const bf16x8 Bf2 = *(const bf16x8*)(&Wt2[nt * 16 + l16][ks * 32 + quad * 8]);
                facc[nt] = __builtin_amdgcn_mfma_f32_16x16x32_bf16(Tf[ks], Bf2, facc[nt], 0, 0, 0);
            }
        #pragma unroll
        for (int nt = 0; nt < 6; ++nt) {
            const int col = nt * 16 + l16;
            #pragma unroll
            for (int r = 0; r < 4; ++r) {
                const int row = row0 + quad * 4 + r;
                const size_t o = (size_t)row * H + col;
                outp[o] = A[o] + gelu_erf(facc[nt][r] + bv2[nt]);
            }
        }
    }
}

extern "C" void kernel_launch(void* const* d_in, const int* in_sizes, int n_in,
                              void* d_out, int out_size, void* d_ws, size_t ws_size,
                              hipStream_t stream)
{
    const float* x_feat = (const float*)d_in[0];
    const float* bases  = (const float*)d_in[1];
    const float* W_pre  = (const float*)d_in[2];
    const float* b_pre  = (const float*)d_in[3];
    const float* W1     = (const float*)d_in[4];
    const float* b1     = (const float*)d_in[5];
    const float* W2     = (const float*)d_in[6];
    const float* b2     = (const float*)d_in[7];
    const int* src = (const int*)d_in[8];
    const int* dst = (const int*)d_in[9];

    char* ws = (char*)d_ws;
    int*            cursor = (int*)(ws);                       // 200,000 B
    int2*           csr2   = (int2*)(ws + 1048576);            // 25,600,000 B
    unsigned short* h_bf   = (unsigned short*)(ws + 27262976); // 9,600,000 B
    float*          xb     = (float*)(ws + 37748736);          // 19,200,000 B
    float*          out    = (float*)d_out;

    const int nStrips = NODES / 16;                            // 3125 exact

    // h = gelu(x_feat @ W_pre + b_pre) -> bf16; also init cursor
    gemm96_pre<<<512, 256, 0, stream>>>(x_feat, W_pre, b_pre, h_bf, cursor, nStrips);
    // padded-bucket CSR scatter
    build_csr2<<<(EDGES + 255) / 256, 256, 0, stream>>>(dst, src, cursor, csr2);
    // xb = x_feat + pull-sum(h[src]*bases)  -- full-occupancy latency hiding
    gather_nodes<<<(NODES * 12 + 255) / 256, 256, 0, stream>>>(
        h_bf, bases, csr2, cursor, x_feat, xb);
    // out = xb + gelu(gelu(xb@W1+b1)@W2+b2)
    ffn_dual<<<512, 256, 0, stream>>>(xb, W1, b1, W2, b2, out, nStrips);
}